// Round 3
// baseline (158.210 us; speedup 1.0000x reference)
//
#include <hip/hip_runtime.h>
#include <hip/hip_bf16.h>
#include <stdint.h>

#define BB 4
#define NN 2048
#define FF 128

typedef __attribute__((ext_vector_type(8))) short bf16x8;
typedef __attribute__((ext_vector_type(4))) float f32x4;

__device__ inline unsigned pk_bf16(float a, float b) {
    union { float f; unsigned u; } x, y;
    x.f = a; y.f = b;
    unsigned xu = x.u + (0x7fffu + ((x.u >> 16) & 1u));
    unsigned yu = y.u + (0x7fffu + ((y.u >> 16) & 1u));
    return (xu >> 16) | (yu & 0xffff0000u);
}

#define XT_P 136   // bf16 pitch (128 + 8 pad), keeps 16B alignment, breaks bank stride
#define WT_P 136

// ---------------- Kernel 1: h = x@W via bf16 MFMA, s = h@a_w + a_b, Ht bf16 ---------
// grid: BB * (NN/16) = 512 blocks, 256 threads (4 waves), 16 rows/block.
// LDS ~39KB -> 2+ blocks/CU. Wave w owns g-tiles {2w, 2w+1}.
__global__ __launch_bounds__(256) void k1_proj(
    const float* __restrict__ x, const float* __restrict__ W,
    const float* __restrict__ a_w, const float* __restrict__ a_b,
    uint16_t* __restrict__ Ht, float* __restrict__ s_out)
{
    __shared__ uint16_t xt[16 * XT_P];     // bf16 x-tile [n][k]
    __shared__ uint16_t Wt[128 * WT_P];    // bf16 W^T [g][k]
    __shared__ float sredw[4 * 16];

    const int t = threadIdx.x;
    const int w = t >> 6, l = t & 63;
    const int m16 = l & 15, q = l >> 4;
    const int b = blockIdx.x >> 7;
    const int n0 = (blockIdx.x & 127) << 4;

    // stage x-tile (convert to bf16): thread -> (row, 8 cols)
    {
        const int row = t >> 4, c0 = (t & 15) * 8;
        const float* xr = x + ((size_t)(b * NN + n0 + row)) * FF + c0;
        const float4 v0 = *(const float4*)xr;
        const float4 v1 = *(const float4*)(xr + 4);
        unsigned* dst = (unsigned*)(xt + row * XT_P + c0);
        dst[0] = pk_bf16(v0.x, v0.y); dst[1] = pk_bf16(v0.z, v0.w);
        dst[2] = pk_bf16(v1.x, v1.y); dst[3] = pk_bf16(v1.z, v1.w);
    }
    // stage W^T (convert + transpose): thread -> (4 g's, 16 k's)
    {
        const int c4 = (t & 31) * 4, kh = (t >> 5) * 16;
        #pragma unroll
        for (int kk = 0; kk < 16; kk += 2) {
            const int k = kh + kk;
            const float4 r0 = *(const float4*)(W + (size_t)k * 128 + c4);
            const float4 r1 = *(const float4*)(W + (size_t)(k + 1) * 128 + c4);
            *(unsigned*)(Wt + (c4 + 0) * WT_P + k) = pk_bf16(r0.x, r1.x);
            *(unsigned*)(Wt + (c4 + 1) * WT_P + k) = pk_bf16(r0.y, r1.y);
            *(unsigned*)(Wt + (c4 + 2) * WT_P + k) = pk_bf16(r0.z, r1.z);
            *(unsigned*)(Wt + (c4 + 3) * WT_P + k) = pk_bf16(r0.w, r1.w);
        }
    }
    const int g0 = (2 * w) * 16 + m16, g1 = (2 * w + 1) * 16 + m16;
    const float aw0 = a_w[g0], aw1 = a_w[g1];
    __syncthreads();

    f32x4 acc0 = {}, acc1 = {};
    bf16x8 af[4];
    #pragma unroll
    for (int dk = 0; dk < 4; ++dk)
        af[dk] = *(const bf16x8*)(xt + m16 * XT_P + dk * 32 + q * 8);
    #pragma unroll
    for (int dk = 0; dk < 4; ++dk) {
        bf16x8 b0 = *(const bf16x8*)(Wt + g0 * WT_P + dk * 32 + q * 8);
        bf16x8 b1 = *(const bf16x8*)(Wt + g1 * WT_P + dk * 32 + q * 8);
        acc0 = __builtin_amdgcn_mfma_f32_16x16x32_bf16(af[dk], b0, acc0, 0, 0, 0);
        acc1 = __builtin_amdgcn_mfma_f32_16x16x32_bf16(af[dk], b1, acc1, 0, 0, 0);
    }

    // s partials: lane holds rows q*4+r for cols g0,g1 -> reduce over m16 lanes
    float sp[4];
    #pragma unroll
    for (int r = 0; r < 4; ++r) sp[r] = acc0[r] * aw0 + acc1[r] * aw1;
    #pragma unroll
    for (int off = 1; off < 16; off <<= 1)
        #pragma unroll
        for (int r = 0; r < 4; ++r) sp[r] += __shfl_xor(sp[r], off, 64);
    if (m16 == 0) {
        #pragma unroll
        for (int r = 0; r < 4; ++r) sredw[w * 16 + q * 4 + r] = sp[r];
    }

    // Ht[b][g][n] bf16: lane holds 4 consecutive n = n0 + q*4 + r for its g
    {
        uint2 o0 = { pk_bf16(acc0[0], acc0[1]), pk_bf16(acc0[2], acc0[3]) };
        uint2 o1 = { pk_bf16(acc1[0], acc1[1]), pk_bf16(acc1[2], acc1[3]) };
        *(uint2*)(Ht + ((size_t)(b * 128 + g0)) * NN + n0 + q * 4) = o0;
        *(uint2*)(Ht + ((size_t)(b * 128 + g1)) * NN + n0 + q * 4) = o1;
    }
    __syncthreads();
    if (t < 16)
        s_out[b * NN + n0 + t] = sredw[t] + sredw[16 + t] + sredw[32 + t] + sredw[48 + t] + a_b[0];
}

// ---------------- Kernel 2: fused scores + softmax + P@H ----------------------------
// grid: BB * (NN/16) = 512 blocks, 512 threads (8 waves) -> 16 waves/CU.
// Wave w owns chunks c == w (mod 8). sched_barrier pins the 12-load batch
// (8 hb + 4 prefetch) before VALU/MFMA so all stay in flight (forces hb live).
__global__ __launch_bounds__(512, 4) void k2_attn(
    const float* __restrict__ A, const uint16_t* __restrict__ Ht,
    const float* __restrict__ s, const float* __restrict__ bias,
    float* __restrict__ out)
{
    __shared__ float Op[16 * 132];
    __shared__ float rsums[16];
    __shared__ float rsp[8 * 64];

    const int t = threadIdx.x;
    const int w = t >> 6, l = t & 63;
    const int b = blockIdx.x >> 7;
    const int i0 = (blockIdx.x & 127) << 4;
    const int m16 = l & 15, q = l >> 4;

    for (int i = t; i < 16 * 132; i += 512) Op[i] = 0.f;
    __syncthreads();

    const float* sb = s + b * NN;
    const float* Arow = A + ((size_t)b * NN + i0 + m16) * NN;
    const uint16_t* Hb = Ht + (size_t)b * 128 * NN;
    const float si = sb[i0 + m16];

    f32x4 acc[8] = {};
    float rs = 0.f;

    const int jq = q * 8;
    float4 a0 = *(const float4*)(Arow + w * 32 + jq);
    float4 a1 = *(const float4*)(Arow + w * 32 + jq + 4);
    float4 s0 = *(const float4*)(sb + w * 32 + jq);
    float4 s1 = *(const float4*)(sb + w * 32 + jq + 4);

    for (int c = w; c < 64; c += 8) {
        const int jbc = c * 32 + jq;

        bf16x8 hb[8];
        #pragma unroll
        for (int t8 = 0; t8 < 8; ++t8)
            hb[t8] = *(const bf16x8*)(Hb + ((size_t)(t8 * 16 + m16)) * NN + jbc);

        const int jn = ((c + 8) & 63) * 32 + jq;
        float4 na0 = *(const float4*)(Arow + jn);
        float4 na1 = *(const float4*)(Arow + jn + 4);
        float4 ns0 = *(const float4*)(sb + jn);
        float4 ns1 = *(const float4*)(sb + jn + 4);

        __builtin_amdgcn_sched_barrier(0);   // pin all 12 loads before compute

        const float sj[8] = {s0.x, s0.y, s0.z, s0.w, s1.x, s1.y, s1.z, s1.w};
        const float av[8] = {a0.x, a0.y, a0.z, a0.w, a1.x, a1.y, a1.z, a1.w};

        float p[8];
        #pragma unroll
        for (int j = 0; j < 8; ++j) {
            float e = si + sj[j];
            e = fmaxf(e, 0.2f * e);                  // LeakyReLU(0.2)
            p[j] = __expf(e + av[j]);
            rs += p[j];
        }
        union { unsigned u[4]; bf16x8 v; } fa;
        #pragma unroll
        for (int j = 0; j < 4; ++j) fa.u[j] = pk_bf16(p[2 * j], p[2 * j + 1]);

        #pragma unroll
        for (int t8 = 0; t8 < 8; ++t8)
            acc[t8] = __builtin_amdgcn_mfma_f32_16x16x32_bf16(fa.v, hb[t8], acc[t8], 0, 0, 0);

        a0 = na0; a1 = na1; s0 = ns0; s1 = ns1;
    }

    rsp[w * 64 + l] = rs;

    #pragma unroll
    for (int t8 = 0; t8 < 8; ++t8)
        #pragma unroll
        for (int r = 0; r < 4; ++r)
            atomicAdd(&Op[(q * 4 + r) * 132 + t8 * 16 + m16], acc[t8][r]);
    __syncthreads();

    if (t < 16) {
        float sum = 0.f;
        #pragma unroll
        for (int w2 = 0; w2 < 8; ++w2)
            #pragma unroll
            for (int q2 = 0; q2 < 4; ++q2)
                sum += rsp[w2 * 64 + q2 * 16 + t];
        rsums[t] = sum;
    }
    __syncthreads();

    {
        const int g = t & 127, rh = t >> 7;
        #pragma unroll
        for (int p2 = 0; p2 < 4; ++p2) {
            const int row = rh * 4 + p2;
            out[((size_t)b * NN + i0 + row) * FF + g] = Op[row * 132 + g] / rsums[row] + bias[g];
        }
    }
}

extern "C" void kernel_launch(void* const* d_in, const int* in_sizes, int n_in,
                              void* d_out, int out_size, void* d_ws, size_t ws_size,
                              hipStream_t stream) {
    const float* x    = (const float*)d_in[0];
    const float* A    = (const float*)d_in[1];
    const float* W    = (const float*)d_in[2];
    const float* a_w  = (const float*)d_in[3];
    const float* a_b  = (const float*)d_in[4];
    const float* bias = (const float*)d_in[5];
    float* out = (float*)d_out;

    uint16_t* Ht = (uint16_t*)d_ws;                                   // BB*128*NN bf16 = 2 MB
    float* s = (float*)((char*)d_ws + (size_t)BB * 128 * NN * 2);     // BB*NN fp32

    k1_proj<<<BB * (NN / 16), 256, 0, stream>>>(x, W, a_w, a_b, Ht, s);
    k2_attn<<<BB * (NN / 16), 512, 0, stream>>>(A, Ht, s, bias, out);
}

// Round 4
// 145.470 us; speedup vs baseline: 1.0876x; 1.0876x over previous
//
#include <hip/hip_runtime.h>
#include <hip/hip_bf16.h>
#include <stdint.h>

#define BB 4
#define NN 2048
#define FF 128

typedef __attribute__((ext_vector_type(8))) short bf16x8;
typedef __attribute__((ext_vector_type(4))) float f32x4;

__device__ inline unsigned pk_bf16(float a, float b) {
    union { float f; unsigned u; } x, y;
    x.f = a; y.f = b;
    unsigned xu = x.u + (0x7fffu + ((x.u >> 16) & 1u));
    unsigned yu = y.u + (0x7fffu + ((y.u >> 16) & 1u));
    return (xu >> 16) | (yu & 0xffff0000u);
}

// fire-and-forget global->LDS DMA, 16B/lane; LDS dest is wave-uniform base + lane*16
__device__ inline void glds16(const void* g, void* l) {
    __builtin_amdgcn_global_load_lds((const __attribute__((address_space(1))) void*)g,
                                     (__attribute__((address_space(3))) void*)l, 16, 0, 0);
}

#define XT_P 136
#define WT_P 136

// ---------------- Kernel 1: h = x@W via bf16 MFMA, s = h@a_w + a_b, Ht bf16 ---------
__global__ __launch_bounds__(256) void k1_proj(
    const float* __restrict__ x, const float* __restrict__ W,
    const float* __restrict__ a_w, const float* __restrict__ a_b,
    uint16_t* __restrict__ Ht, float* __restrict__ s_out)
{
    __shared__ uint16_t xt[16 * XT_P];
    __shared__ uint16_t Wt[128 * WT_P];
    __shared__ float sredw[4 * 16];

    const int t = threadIdx.x;
    const int w = t >> 6, l = t & 63;
    const int m16 = l & 15, q = l >> 4;
    const int b = blockIdx.x >> 7;
    const int n0 = (blockIdx.x & 127) << 4;

    // batch-load W rows into regs first (no serial load->write chain)
    const int c4 = (t & 31) * 4, kh = (t >> 5) * 16;
    float4 wr0[8], wr1[8];
    #pragma unroll
    for (int kk = 0; kk < 8; ++kk) {
        const int k = kh + 2 * kk;
        wr0[kk] = *(const float4*)(W + (size_t)k * 128 + c4);
        wr1[kk] = *(const float4*)(W + (size_t)(k + 1) * 128 + c4);
    }
    // stage x-tile (convert to bf16)
    {
        const int row = t >> 4, c0 = (t & 15) * 8;
        const float* xr = x + ((size_t)(b * NN + n0 + row)) * FF + c0;
        const float4 v0 = *(const float4*)xr;
        const float4 v1 = *(const float4*)(xr + 4);
        unsigned* dst = (unsigned*)(xt + row * XT_P + c0);
        dst[0] = pk_bf16(v0.x, v0.y); dst[1] = pk_bf16(v0.z, v0.w);
        dst[2] = pk_bf16(v1.x, v1.y); dst[3] = pk_bf16(v1.z, v1.w);
    }
    // write W^T (bf16, transposed) from regs
    #pragma unroll
    for (int kk = 0; kk < 8; ++kk) {
        const int k = kh + 2 * kk;
        *(unsigned*)(Wt + (c4 + 0) * WT_P + k) = pk_bf16(wr0[kk].x, wr1[kk].x);
        *(unsigned*)(Wt + (c4 + 1) * WT_P + k) = pk_bf16(wr0[kk].y, wr1[kk].y);
        *(unsigned*)(Wt + (c4 + 2) * WT_P + k) = pk_bf16(wr0[kk].z, wr1[kk].z);
        *(unsigned*)(Wt + (c4 + 3) * WT_P + k) = pk_bf16(wr0[kk].w, wr1[kk].w);
    }
    const int g0 = (2 * w) * 16 + m16, g1 = (2 * w + 1) * 16 + m16;
    const float aw0 = a_w[g0], aw1 = a_w[g1];
    __syncthreads();

    f32x4 acc0 = {}, acc1 = {};
    bf16x8 af[4];
    #pragma unroll
    for (int dk = 0; dk < 4; ++dk)
        af[dk] = *(const bf16x8*)(xt + m16 * XT_P + dk * 32 + q * 8);
    #pragma unroll
    for (int dk = 0; dk < 4; ++dk) {
        bf16x8 b0 = *(const bf16x8*)(Wt + g0 * WT_P + dk * 32 + q * 8);
        bf16x8 b1 = *(const bf16x8*)(Wt + g1 * WT_P + dk * 32 + q * 8);
        acc0 = __builtin_amdgcn_mfma_f32_16x16x32_bf16(af[dk], b0, acc0, 0, 0, 0);
        acc1 = __builtin_amdgcn_mfma_f32_16x16x32_bf16(af[dk], b1, acc1, 0, 0, 0);
    }

    float sp[4];
    #pragma unroll
    for (int r = 0; r < 4; ++r) sp[r] = acc0[r] * aw0 + acc1[r] * aw1;
    #pragma unroll
    for (int off = 1; off < 16; off <<= 1)
        #pragma unroll
        for (int r = 0; r < 4; ++r) sp[r] += __shfl_xor(sp[r], off, 64);
    if (m16 == 0) {
        #pragma unroll
        for (int r = 0; r < 4; ++r) sredw[w * 16 + q * 4 + r] = sp[r];
    }
    {
        uint2 o0 = { pk_bf16(acc0[0], acc0[1]), pk_bf16(acc0[2], acc0[3]) };
        uint2 o1 = { pk_bf16(acc1[0], acc1[1]), pk_bf16(acc1[2], acc1[3]) };
        *(uint2*)(Ht + ((size_t)(b * 128 + g0)) * NN + n0 + q * 4) = o0;
        *(uint2*)(Ht + ((size_t)(b * 128 + g1)) * NN + n0 + q * 4) = o1;
    }
    __syncthreads();
    if (t < 16)
        s_out[b * NN + n0 + t] = sredw[t] + sredw[16 + t] + sredw[32 + t] + sredw[48 + t] + a_b[0];
}

// ---------------- Kernel 2: fused scores + softmax + P@H, LDS-staged pipeline --------
// grid BB*(NN/16)=512 blocks, 256 threads (4 waves). Round = 64 j, double-buffered:
// Ht-tile staged via global_load_lds (fire-and-forget), A-tile via reg->ds_write.
// Wave w: wo=w&1 picks j-interleave (j = q*16 + wo*8 + jj), gh=w>>1 picks g-half.
#define JR 64
#define NR (NN / JR)
#define HT_GRP 1040              // 8 rows * 128B + 16B pad (bank-uniform frag reads)
#define HT_TILE (16 * HT_GRP)
#define AT_P 68

__global__ __launch_bounds__(256, 2) void k2_attn(
    const float* __restrict__ A, const uint16_t* __restrict__ Ht,
    const float* __restrict__ s, const float* __restrict__ bias,
    float* __restrict__ out)
{
    __shared__ uint8_t htb[2][HT_TILE];
    __shared__ float atb[2][16 * AT_P];
    __shared__ float Op[16 * 132];
    __shared__ float rsums[16];
    __shared__ float rsp[2 * 64];

    const int t = threadIdx.x;
    const int w = t >> 6, l = t & 63;
    const int m16 = l & 15, q = l >> 4;
    const int wo = w & 1, gh = w >> 1;
    const int b = blockIdx.x >> 7;
    const int i0 = (blockIdx.x & 127) << 4;

    for (int i = t; i < 16 * 132; i += 256) Op[i] = 0.f;

    const float* sb = s + b * NN;
    const float* Ab = A + (size_t)b * NN * NN;
    const uint16_t* Hb = Ht + (size_t)b * 128 * NN;
    const float si = sb[i0 + m16];
    const float* Ast = Ab + (size_t)(i0 + (t >> 4)) * NN + (t & 15) * 4;
    const int sjo = q * 16 + wo * 8;

    // ---- prologue: stage round 0 ----
    #pragma unroll
    for (int u = 0; u < 4; ++u) {
        const int gg = w * 4 + u;
        glds16(Hb + (size_t)(gg * 8 + (l >> 3)) * NN + (l & 7) * 8, htb[0] + gg * HT_GRP);
    }
    {
        float4 a0 = *(const float4*)Ast;
        *(float4*)&atb[0][(t >> 4) * AT_P + (t & 15) * 4] = a0;
    }
    float4 sj0 = *(const float4*)(sb + sjo);
    float4 sj1 = *(const float4*)(sb + sjo + 4);
    __syncthreads();

    f32x4 acc[4] = {};
    float rs = 0.f;

    for (int r = 0; r < NR; ++r) {
        const int cur = r & 1, nxt = cur ^ 1;
        const int j1 = ((r + 1) & (NR - 1)) * JR;   // wraps on last iter (harmless)

        // stage next round: Ht via glds (no VGPR dest -> cannot be serialized)
        #pragma unroll
        for (int u = 0; u < 4; ++u) {
            const int gg = w * 4 + u;
            glds16(Hb + (size_t)(gg * 8 + (l >> 3)) * NN + j1 + (l & 7) * 8,
                   htb[nxt] + gg * HT_GRP);
        }
        float4 na = *(const float4*)(Ast + j1);
        float4 ns0 = *(const float4*)(sb + j1 + sjo);
        float4 ns1 = *(const float4*)(sb + j1 + sjo + 4);

        // compute current round from LDS
        const float* ar = &atb[cur][m16 * AT_P + sjo];
        float4 af0 = *(const float4*)ar;
        float4 af1 = *(const float4*)(ar + 4);
        const float sjv[8] = {sj0.x, sj0.y, sj0.z, sj0.w, sj1.x, sj1.y, sj1.z, sj1.w};
        const float avv[8] = {af0.x, af0.y, af0.z, af0.w, af1.x, af1.y, af1.z, af1.w};
        float p[8];
        #pragma unroll
        for (int j = 0; j < 8; ++j) {
            float e = si + sjv[j];
            e = fmaxf(e, 0.2f * e);                 // LeakyReLU(0.2)
            p[j] = __expf(e + avv[j]);
            rs += p[j];
        }
        union { unsigned u[4]; bf16x8 v; } fa;
        #pragma unroll
        for (int j = 0; j < 4; ++j) fa.u[j] = pk_bf16(p[2 * j], p[2 * j + 1]);

        #pragma unroll
        for (int t4 = 0; t4 < 4; ++t4) {
            const int g = gh * 64 + t4 * 16 + m16;
            const uint16_t* hp = (const uint16_t*)(htb[cur] + (g >> 3) * HT_GRP + (g & 7) * 128) + sjo;
            bf16x8 hb = *(const bf16x8*)hp;
            acc[t4] = __builtin_amdgcn_mfma_f32_16x16x32_bf16(fa.v, hb, acc[t4], 0, 0, 0);
        }

        // hand off next-round A/s
        *(float4*)&atb[nxt][(t >> 4) * AT_P + (t & 15) * 4] = na;
        sj0 = ns0; sj1 = ns1;
        __syncthreads();
    }

    // waves 0,1 (gh=0, wo=0/1) cover all j exactly once -> row sums
    if (w < 2) rsp[w * 64 + l] = rs;

    #pragma unroll
    for (int t4 = 0; t4 < 4; ++t4)
        #pragma unroll
        for (int r2 = 0; r2 < 4; ++r2)
            atomicAdd(&Op[(q * 4 + r2) * 132 + gh * 64 + t4 * 16 + m16], acc[t4][r2]);
    __syncthreads();

    if (t < 16) {
        float sum = 0.f;
        #pragma unroll
        for (int w2 = 0; w2 < 2; ++w2)
            #pragma unroll
            for (int q2 = 0; q2 < 4; ++q2)
                sum += rsp[w2 * 64 + q2 * 16 + t];
        rsums[t] = sum;
    }
    __syncthreads();

    {
        const int g = t & 127, rh = t >> 7;
        #pragma unroll
        for (int p2 = 0; p2 < 8; ++p2) {
            const int row = rh * 8 + p2;
            out[((size_t)b * NN + i0 + row) * FF + g] = Op[row * 132 + g] / rsums[row] + bias[g];
        }
    }
}

extern "C" void kernel_launch(void* const* d_in, const int* in_sizes, int n_in,
                              void* d_out, int out_size, void* d_ws, size_t ws_size,
                              hipStream_t stream) {
    const float* x    = (const float*)d_in[0];
    const float* A    = (const float*)d_in[1];
    const float* W    = (const float*)d_in[2];
    const float* a_w  = (const float*)d_in[3];
    const float* a_b  = (const float*)d_in[4];
    const float* bias = (const float*)d_in[5];
    float* out = (float*)d_out;

    uint16_t* Ht = (uint16_t*)d_ws;                                   // BB*128*NN bf16 = 2 MB
    float* s = (float*)((char*)d_ws + (size_t)BB * 128 * NN * 2);     // BB*NN fp32

    k1_proj<<<BB * (NN / 16), 256, 0, stream>>>(x, W, a_w, a_b, Ht, s);
    k2_attn<<<BB * (NN / 16), 256, 0, stream>>>(A, Ht, s, bias, out);
}

// Round 5
// 141.759 us; speedup vs baseline: 1.1161x; 1.0262x over previous
//
#include <hip/hip_runtime.h>
#include <hip/hip_bf16.h>
#include <stdint.h>

#define BB 4
#define NN 2048
#define FF 128

typedef __attribute__((ext_vector_type(8))) short bf16x8;
typedef __attribute__((ext_vector_type(4))) float f32x4;

__device__ inline unsigned pk_bf16(float a, float b) {
    union { float f; unsigned u; } x, y;
    x.f = a; y.f = b;
    unsigned xu = x.u + (0x7fffu + ((x.u >> 16) & 1u));
    unsigned yu = y.u + (0x7fffu + ((y.u >> 16) & 1u));
    return (xu >> 16) | (yu & 0xffff0000u);
}
__device__ inline uint16_t b16(float v) {
    union { float f; unsigned u; } c; c.f = v;
    return (uint16_t)((c.u + (0x7fffu + ((c.u >> 16) & 1u))) >> 16);
}
__device__ inline void glds16(const void* g, void* l) {
    __builtin_amdgcn_global_load_lds((const __attribute__((address_space(1))) void*)g,
                                     (__attribute__((address_space(3))) void*)l, 16, 0, 0);
}

#define XT_P 136
#define WT_P 136

// ---------------- Kernel 1: h = x@W via bf16 MFMA, s = h@a_w + a_b, Ht bf16 ---------
__global__ __launch_bounds__(256) void k1_proj(
    const float* __restrict__ x, const float* __restrict__ W,
    const float* __restrict__ a_w, const float* __restrict__ a_b,
    uint16_t* __restrict__ Ht, float* __restrict__ s_out)
{
    __shared__ uint16_t xt[16 * XT_P];
    __shared__ uint16_t Wt[128 * WT_P];
    __shared__ float sredw[4 * 16];

    const int t = threadIdx.x;
    const int w = t >> 6, l = t & 63;
    const int m16 = l & 15, q = l >> 4;
    const int b = blockIdx.x >> 7;
    const int n0 = (blockIdx.x & 127) << 4;

    const int c4 = (t & 31) * 4, kh = (t >> 5) * 16;
    float4 wr0[8], wr1[8];
    #pragma unroll
    for (int kk = 0; kk < 8; ++kk) {
        const int k = kh + 2 * kk;
        wr0[kk] = *(const float4*)(W + (size_t)k * 128 + c4);
        wr1[kk] = *(const float4*)(W + (size_t)(k + 1) * 128 + c4);
    }
    {
        const int row = t >> 4, c0 = (t & 15) * 8;
        const float* xr = x + ((size_t)(b * NN + n0 + row)) * FF + c0;
        const float4 v0 = *(const float4*)xr;
        const float4 v1 = *(const float4*)(xr + 4);
        unsigned* dst = (unsigned*)(xt + row * XT_P + c0);
        dst[0] = pk_bf16(v0.x, v0.y); dst[1] = pk_bf16(v0.z, v0.w);
        dst[2] = pk_bf16(v1.x, v1.y); dst[3] = pk_bf16(v1.z, v1.w);
    }
    #pragma unroll
    for (int kk = 0; kk < 8; ++kk) {
        const int k = kh + 2 * kk;
        *(unsigned*)(Wt + (c4 + 0) * WT_P + k) = pk_bf16(wr0[kk].x, wr1[kk].x);
        *(unsigned*)(Wt + (c4 + 1) * WT_P + k) = pk_bf16(wr0[kk].y, wr1[kk].y);
        *(unsigned*)(Wt + (c4 + 2) * WT_P + k) = pk_bf16(wr0[kk].z, wr1[kk].z);
        *(unsigned*)(Wt + (c4 + 3) * WT_P + k) = pk_bf16(wr0[kk].w, wr1[kk].w);
    }
    const int g0 = (2 * w) * 16 + m16, g1 = (2 * w + 1) * 16 + m16;
    const float aw0 = a_w[g0], aw1 = a_w[g1];
    __syncthreads();

    f32x4 acc0 = {}, acc1 = {};
    bf16x8 af[4];
    #pragma unroll
    for (int dk = 0; dk < 4; ++dk)
        af[dk] = *(const bf16x8*)(xt + m16 * XT_P + dk * 32 + q * 8);
    #pragma unroll
    for (int dk = 0; dk < 4; ++dk) {
        bf16x8 b0 = *(const bf16x8*)(Wt + g0 * WT_P + dk * 32 + q * 8);
        bf16x8 b1 = *(const bf16x8*)(Wt + g1 * WT_P + dk * 32 + q * 8);
        acc0 = __builtin_amdgcn_mfma_f32_16x16x32_bf16(af[dk], b0, acc0, 0, 0, 0);
        acc1 = __builtin_amdgcn_mfma_f32_16x16x32_bf16(af[dk], b1, acc1, 0, 0, 0);
    }

    float sp[4];
    #pragma unroll
    for (int r = 0; r < 4; ++r) sp[r] = acc0[r] * aw0 + acc1[r] * aw1;
    #pragma unroll
    for (int off = 1; off < 16; off <<= 1)
        #pragma unroll
        for (int r = 0; r < 4; ++r) sp[r] += __shfl_xor(sp[r], off, 64);
    if (m16 == 0) {
        #pragma unroll
        for (int r = 0; r < 4; ++r) sredw[w * 16 + q * 4 + r] = sp[r];
    }
    {
        uint2 o0 = { pk_bf16(acc0[0], acc0[1]), pk_bf16(acc0[2], acc0[3]) };
        uint2 o1 = { pk_bf16(acc1[0], acc1[1]), pk_bf16(acc1[2], acc1[3]) };
        *(uint2*)(Ht + ((size_t)(b * 128 + g0)) * NN + n0 + q * 4) = o0;
        *(uint2*)(Ht + ((size_t)(b * 128 + g1)) * NN + n0 + q * 4) = o1;
    }
    __syncthreads();
    if (t < 16)
        s_out[b * NN + n0 + t] = sredw[t] + sredw[16 + t] + sredw[32 + t] + sredw[48 + t] + a_b[0];
}

// ---------------- Kernel 2: split-K fused attention, FAT rounds ----------------------
// Block = (b, i-range 256, j-range 256). Grid 256 = 1 block/CU. Ht[*, jrange]
// staged ONCE (64KB LDS, xor-swizzled). 16 i-tile rounds; per round: 16KB A-tile
// glds (dbuf), P->LDS, 16 MFMA, bf16 partial-out stores. Bytes-per-barrier-drain
// ~24KB/CU => BW-saturating despite per-round vmcnt(0) drains.
#define JS 8
#define JRR 256
#define NRND 16

__global__ __launch_bounds__(256) void k2_attn(
    const float* __restrict__ A, const uint16_t* __restrict__ Ht,
    const float* __restrict__ s, uint16_t* __restrict__ po,
    float* __restrict__ prs)
{
    __shared__ uint16_t hts[128 * 256];   // 64KB, [g][granule(16B) xor (g&7)]
    __shared__ float abuf[2][16 * 256];   // 2x16KB, [i][granule xor (i&7)]
    __shared__ uint16_t pbuf[16 * 256];   // 8KB,  [i][granule xor (i&7)]
    __shared__ float rsLds[256];

    const int t = threadIdx.x;
    const int w = t >> 6, l = t & 63;
    const int m16 = l & 15, q = l >> 4;

    const int bx = blockIdx.x;
    const int is = bx & 7;
    const int js = (bx >> 3) & 7;
    const int b  = bx >> 6;
    const int j0 = js * JRR;
    const int i0 = is * 256;

    const float* sb = s + b * NN;
    const float* Ab = A + (size_t)b * NN * NN;
    const uint16_t* Hb = Ht + (size_t)b * FF * NN;

    // loop-invariant sj for this lane's 16 j's (kk = 2w, 2w+1; offset q*8)
    const int jA = 2 * w * 32 + q * 8;
    float4 sj0 = *(const float4*)(sb + j0 + jA);
    float4 sj1 = *(const float4*)(sb + j0 + jA + 4);
    float4 sj2 = *(const float4*)(sb + j0 + jA + 32);
    float4 sj3 = *(const float4*)(sb + j0 + jA + 36);

    // prologue: stage hts (wave w: rows 32w..32w+31; 2 rows per glds)
    #pragma unroll
    for (int u = 0; u < 16; ++u) {
        const int row = 32 * w + 2 * u + (l >> 5);
        const int c = l & 31;
        glds16(Hb + (size_t)row * NN + j0 + 8 * (c ^ (row & 7)),
               hts + (32 * w + 2 * u) * 256);
    }
    // stage A round 0 (wave w: rows 4w..4w+3; 1 row per glds)
    #pragma unroll
    for (int u = 0; u < 4; ++u) {
        const int row = 4 * w + u;
        glds16(Ab + (size_t)(i0 + row) * NN + j0 + 4 * (l ^ (row & 7)),
               &abuf[0][row * 256]);
    }
    __syncthreads();

    for (int r = 0; r < NRND; ++r) {
        const int cur = r & 1, nxt = cur ^ 1;
        const int rn = (r + 1) & (NRND - 1);

        // prefetch next A-tile (fire-and-forget; drained at this round's barrier)
        #pragma unroll
        for (int u = 0; u < 4; ++u) {
            const int row = 4 * w + u;
            glds16(Ab + (size_t)(i0 + rn * 16 + row) * NN + j0 + 4 * (l ^ (row & 7)),
                   &abuf[nxt][row * 256]);
        }
        const float si = sb[i0 + r * 16 + m16];

        // read this lane's A values (granules kk*8+2q, +1 for kk=2w,2w+1)
        const int ga0 = (2 * w) * 8 + 2 * q;
        const int ga1 = (2 * w + 1) * 8 + 2 * q;
        const float* ac = &abuf[cur][m16 * 256];
        const int x7 = m16 & 7;
        float4 a0 = *(const float4*)(ac + 4 * (ga0 ^ x7));
        float4 a1 = *(const float4*)(ac + 4 * ((ga0 + 1) ^ x7));
        float4 a2 = *(const float4*)(ac + 4 * (ga1 ^ x7));
        float4 a3 = *(const float4*)(ac + 4 * ((ga1 + 1) ^ x7));

        const float sv[16] = {sj0.x,sj0.y,sj0.z,sj0.w, sj1.x,sj1.y,sj1.z,sj1.w,
                              sj2.x,sj2.y,sj2.z,sj2.w, sj3.x,sj3.y,sj3.z,sj3.w};
        const float av[16] = {a0.x,a0.y,a0.z,a0.w, a1.x,a1.y,a1.z,a1.w,
                              a2.x,a2.y,a2.z,a2.w, a3.x,a3.y,a3.z,a3.w};
        float pv[16]; float rs = 0.f;
        #pragma unroll
        for (int j = 0; j < 16; ++j) {
            float e = si + sv[j];
            e = fmaxf(e, 0.2f * e);             // LeakyReLU(0.2)
            pv[j] = __expf(e + av[j]);
            rs += pv[j];
        }
        union { unsigned u[4]; bf16x8 v; } pk0, pk1;
        #pragma unroll
        for (int j = 0; j < 4; ++j) {
            pk0.u[j] = pk_bf16(pv[2 * j], pv[2 * j + 1]);
            pk1.u[j] = pk_bf16(pv[8 + 2 * j], pv[9 + 2 * j]);
        }
        *(bf16x8*)(pbuf + m16 * 256 + 8 * ((8 * w + q) ^ x7)) = pk0.v;
        *(bf16x8*)(pbuf + m16 * 256 + 8 * ((8 * w + 4 + q) ^ x7)) = pk1.v;
        rsLds[t] = rs;
        __syncthreads();   // P ready; drains A(next) glds (fat-round by design)

        // MFMA: wave w owns g in [32w, 32w+32)
        f32x4 acc0 = {}, acc1 = {};
        const int gA = w * 32 + m16, gB = w * 32 + 16 + m16;
        #pragma unroll
        for (int kk = 0; kk < 8; ++kk) {
            const int jc = kk * 4 + q;
            bf16x8 af = *(const bf16x8*)(pbuf + m16 * 256 + 8 * (jc ^ x7));
            bf16x8 h0 = *(const bf16x8*)(hts + gA * 256 + 8 * (jc ^ x7));
            bf16x8 h1 = *(const bf16x8*)(hts + gB * 256 + 8 * (jc ^ x7));
            acc0 = __builtin_amdgcn_mfma_f32_16x16x32_bf16(af, h0, acc0, 0, 0, 0);
            acc1 = __builtin_amdgcn_mfma_f32_16x16x32_bf16(af, h1, acc1, 0, 0, 0);
        }

        if (t < 16) {
            float sum = 0.f;
            #pragma unroll
            for (int w2 = 0; w2 < 4; ++w2)
                #pragma unroll
                for (int q2 = 0; q2 < 4; ++q2)
                    sum += rsLds[w2 * 64 + q2 * 16 + t];
            prs[(size_t)(js * BB + b) * NN + i0 + r * 16 + t] = sum;
        }

        const size_t pob = ((size_t)(js * BB + b) * NN + i0 + r * 16) * FF;
        #pragma unroll
        for (int rr = 0; rr < 4; ++rr) {
            const int irow = q * 4 + rr;
            po[pob + (size_t)irow * FF + w * 32 + m16]      = b16(acc0[rr]);
            po[pob + (size_t)irow * FF + w * 32 + 16 + m16] = b16(acc1[rr]);
        }
        __syncthreads();   // pbuf/rsLds/abuf reuse fence
    }
}

// ---------------- Kernel 3: reduce 8 partials, normalize, bias ----------------------
__global__ __launch_bounds__(256) void k3_red(
    const uint16_t* __restrict__ po, const float* __restrict__ prs,
    const float* __restrict__ bias, float* __restrict__ out)
{
    const int idx = blockIdx.x * 256 + threadIdx.x;
    const int g = idx & 127;
    const int i = (idx >> 7) & (NN - 1);
    const int b = idx >> 18;
    float sum = 0.f, rsum = 0.f;
    #pragma unroll
    for (int js = 0; js < JS; ++js) {
        const size_t base = (size_t)(js * BB + b) * NN + i;
        union { unsigned u; float f; } cv;
        cv.u = ((unsigned)po[base * FF + g]) << 16;
        sum += cv.f;
        rsum += prs[base];
    }
    out[idx] = sum / rsum + bias[g];
}

extern "C" void kernel_launch(void* const* d_in, const int* in_sizes, int n_in,
                              void* d_out, int out_size, void* d_ws, size_t ws_size,
                              hipStream_t stream) {
    const float* x    = (const float*)d_in[0];
    const float* A    = (const float*)d_in[1];
    const float* W    = (const float*)d_in[2];
    const float* a_w  = (const float*)d_in[3];
    const float* a_b  = (const float*)d_in[4];
    const float* bias = (const float*)d_in[5];
    float* out = (float*)d_out;

    char* ws = (char*)d_ws;
    uint16_t* Ht = (uint16_t*)ws;                                  // 2 MB
    float* s = (float*)(ws + 2 * 1024 * 1024);                     // 32 KB (pad to 64K)
    uint16_t* po = (uint16_t*)(ws + 2 * 1024 * 1024 + 65536);      // 16 MB
    float* prs = (float*)(ws + 2 * 1024 * 1024 + 65536 + (size_t)JS * BB * NN * FF * 2);  // 256 KB

    k1_proj<<<BB * (NN / 16), 256, 0, stream>>>(x, W, a_w, a_b, Ht, s);
    k2_attn<<<BB * 8 * 8, 256, 0, stream>>>(A, Ht, s, po, prs);
    k3_red<<<(BB * NN * FF) / 256, 256, 0, stream>>>(po, prs, bias, out);
}

// Round 6
// 134.972 us; speedup vs baseline: 1.1722x; 1.0503x over previous
//
#include <hip/hip_runtime.h>
#include <hip/hip_bf16.h>
#include <stdint.h>

#define BB 4
#define NN 2048
#define FF 128

typedef __attribute__((ext_vector_type(8))) short bf16x8;
typedef __attribute__((ext_vector_type(4))) float f32x4;

__device__ inline unsigned pk_bf16(float a, float b) {
    union { float f; unsigned u; } x, y;
    x.f = a; y.f = b;
    unsigned xu = x.u + (0x7fffu + ((x.u >> 16) & 1u));
    unsigned yu = y.u + (0x7fffu + ((y.u >> 16) & 1u));
    return (xu >> 16) | (yu & 0xffff0000u);
}
__device__ inline uint16_t b16(float v) {
    union { float f; unsigned u; } c; c.f = v;
    return (uint16_t)((c.u + (0x7fffu + ((c.u >> 16) & 1u))) >> 16);
}
__device__ inline void glds16(const void* g, void* l) {
    __builtin_amdgcn_global_load_lds((const __attribute__((address_space(1))) void*)g,
                                     (__attribute__((address_space(3))) void*)l, 16, 0, 0);
}

#define XT_P 136
#define WT_P 136

// ---------------- Kernel 1: h = x@W via bf16 MFMA, s = h@a_w + a_b, Ht bf16 ---------
__global__ __launch_bounds__(256) void k1_proj(
    const float* __restrict__ x, const float* __restrict__ W,
    const float* __restrict__ a_w, const float* __restrict__ a_b,
    uint16_t* __restrict__ Ht, float* __restrict__ s_out)
{
    __shared__ uint16_t xt[16 * XT_P];
    __shared__ uint16_t Wt[128 * WT_P];
    __shared__ float sredw[4 * 16];

    const int t = threadIdx.x;
    const int w = t >> 6, l = t & 63;
    const int m16 = l & 15, q = l >> 4;
    const int b = blockIdx.x >> 7;
    const int n0 = (blockIdx.x & 127) << 4;

    const int c4 = (t & 31) * 4, kh = (t >> 5) * 16;
    float4 wr0[8], wr1[8];
    #pragma unroll
    for (int kk = 0; kk < 8; ++kk) {
        const int k = kh + 2 * kk;
        wr0[kk] = *(const float4*)(W + (size_t)k * 128 + c4);
        wr1[kk] = *(const float4*)(W + (size_t)(k + 1) * 128 + c4);
    }
    {
        const int row = t >> 4, c0 = (t & 15) * 8;
        const float* xr = x + ((size_t)(b * NN + n0 + row)) * FF + c0;
        const float4 v0 = *(const float4*)xr;
        const float4 v1 = *(const float4*)(xr + 4);
        unsigned* dst = (unsigned*)(xt + row * XT_P + c0);
        dst[0] = pk_bf16(v0.x, v0.y); dst[1] = pk_bf16(v0.z, v0.w);
        dst[2] = pk_bf16(v1.x, v1.y); dst[3] = pk_bf16(v1.z, v1.w);
    }
    #pragma unroll
    for (int kk = 0; kk < 8; ++kk) {
        const int k = kh + 2 * kk;
        *(unsigned*)(Wt + (c4 + 0) * WT_P + k) = pk_bf16(wr0[kk].x, wr1[kk].x);
        *(unsigned*)(Wt + (c4 + 1) * WT_P + k) = pk_bf16(wr0[kk].y, wr1[kk].y);
        *(unsigned*)(Wt + (c4 + 2) * WT_P + k) = pk_bf16(wr0[kk].z, wr1[kk].z);
        *(unsigned*)(Wt + (c4 + 3) * WT_P + k) = pk_bf16(wr0[kk].w, wr1[kk].w);
    }
    const int g0 = (2 * w) * 16 + m16, g1 = (2 * w + 1) * 16 + m16;
    const float aw0 = a_w[g0], aw1 = a_w[g1];
    __syncthreads();

    f32x4 acc0 = {}, acc1 = {};
    bf16x8 af[4];
    #pragma unroll
    for (int dk = 0; dk < 4; ++dk)
        af[dk] = *(const bf16x8*)(xt + m16 * XT_P + dk * 32 + q * 8);
    #pragma unroll
    for (int dk = 0; dk < 4; ++dk) {
        bf16x8 b0 = *(const bf16x8*)(Wt + g0 * WT_P + dk * 32 + q * 8);
        bf16x8 b1 = *(const bf16x8*)(Wt + g1 * WT_P + dk * 32 + q * 8);
        acc0 = __builtin_amdgcn_mfma_f32_16x16x32_bf16(af[dk], b0, acc0, 0, 0, 0);
        acc1 = __builtin_amdgcn_mfma_f32_16x16x32_bf16(af[dk], b1, acc1, 0, 0, 0);
    }

    float sp[4];
    #pragma unroll
    for (int r = 0; r < 4; ++r) sp[r] = acc0[r] * aw0 + acc1[r] * aw1;
    #pragma unroll
    for (int off = 1; off < 16; off <<= 1)
        #pragma unroll
        for (int r = 0; r < 4; ++r) sp[r] += __shfl_xor(sp[r], off, 64);
    if (m16 == 0) {
        #pragma unroll
        for (int r = 0; r < 4; ++r) sredw[w * 16 + q * 4 + r] = sp[r];
    }
    {
        uint2 o0 = { pk_bf16(acc0[0], acc0[1]), pk_bf16(acc0[2], acc0[3]) };
        uint2 o1 = { pk_bf16(acc1[0], acc1[1]), pk_bf16(acc1[2], acc1[3]) };
        *(uint2*)(Ht + ((size_t)(b * 128 + g0)) * NN + n0 + q * 4) = o0;
        *(uint2*)(Ht + ((size_t)(b * 128 + g1)) * NN + n0 + q * 4) = o1;
    }
    __syncthreads();
    if (t < 16)
        s_out[b * NN + n0 + t] = sredw[t] + sredw[16 + t] + sredw[32 + t] + sredw[48 + t] + a_b[0];
}

// ---------------- Kernel 2: split-K fused attention, non-draining barriers -----------
// Block = (b, i-range 256, j-range 256). Grid 256 = 1 block/CU. Ht[*, jrange]
// staged ONCE (64KB). Per round: issue A[r+1] glds; s_waitcnt vmcnt(13)+s_barrier
// retires EXACTLY the previous round's 4 glds (per-wave vmem order pinned by asm
// memory clobbers: glds x4 then stores x9 per round; in-order vmcnt retirement);
// raw lgkmcnt barriers elsewhere. A prefetch gets a full round of latency cover.
#define JS 8
#define JRR 256
#define NRND 16

__global__ __launch_bounds__(256) void k2_attn(
    const float* __restrict__ A, const uint16_t* __restrict__ Ht,
    const float* __restrict__ s, uint16_t* __restrict__ po,
    float* __restrict__ prs)
{
    __shared__ uint16_t hts[128 * 256];   // 64KB, [g][granule(16B) xor (g&7)]
    __shared__ float abuf[2][16 * 256];   // 2x16KB, [i][granule xor (i&7)]
    __shared__ uint16_t pbuf[16 * 256];   // 8KB
    __shared__ float rsLds[256];
    __shared__ float sLds[256];           // s[i0..i0+255]

    const int t = threadIdx.x;
    const int w = t >> 6, l = t & 63;
    const int m16 = l & 15, q = l >> 4;
    const int x7 = m16 & 7;

    const int bx = blockIdx.x;
    const int is = bx & 7;
    const int js = (bx >> 3) & 7;
    const int b  = bx >> 6;
    const int j0 = js * JRR;
    const int i0 = is * 256;

    const float* sb = s + b * NN;
    const float* Ab = A + (size_t)b * NN * NN;
    const uint16_t* Hb = Ht + (size_t)b * FF * NN;

    // loop-invariant sj for this lane's 16 j's
    const int jA = 2 * w * 32 + q * 8;
    float4 sj0 = *(const float4*)(sb + j0 + jA);
    float4 sj1 = *(const float4*)(sb + j0 + jA + 4);
    float4 sj2 = *(const float4*)(sb + j0 + jA + 32);
    float4 sj3 = *(const float4*)(sb + j0 + jA + 36);

    // prologue: stage hts, A[0], sLds; full drain via __syncthreads
    #pragma unroll
    for (int u = 0; u < 16; ++u) {
        const int row = 32 * w + 2 * u + (l >> 5);
        const int c = l & 31;
        glds16(Hb + (size_t)row * NN + j0 + 8 * (c ^ (row & 7)),
               hts + (32 * w + 2 * u) * 256);
    }
    #pragma unroll
    for (int u = 0; u < 4; ++u) {
        const int row = 4 * w + u;
        glds16(Ab + (size_t)(i0 + row) * NN + j0 + 4 * (l ^ (row & 7)),
               &abuf[0][row * 256]);
    }
    if (w == 0) glds16(sb + i0 + l * 4, sLds);
    __syncthreads();

    for (int r = 0; r < NRND; ++r) {
        const int cur = r & 1, nxt = cur ^ 1;
        const int rn = (r + 1) & (NRND - 1);

        // stage next A-tile (fire-and-forget, consumed next round)
        #pragma unroll
        for (int u = 0; u < 4; ++u) {
            const int row = 4 * w + u;
            glds16(Ab + (size_t)(i0 + rn * 16 + row) * NN + j0 + 4 * (l ^ (row & 7)),
                   &abuf[nxt][row * 256]);
        }
        // retire previous round's glds (13 younger ops: 9 stores + 4 new glds),
        // then cross-wave visibility barrier. Does NOT drain the new prefetch.
        asm volatile("s_waitcnt vmcnt(13)\n\ts_barrier" ::: "memory");

        const float si = sLds[r * 16 + m16];

        const int ga0 = (2 * w) * 8 + 2 * q;
        const int ga1 = (2 * w + 1) * 8 + 2 * q;
        const float* ac = &abuf[cur][m16 * 256];
        float4 a0 = *(const float4*)(ac + 4 * (ga0 ^ x7));
        float4 a1 = *(const float4*)(ac + 4 * ((ga0 + 1) ^ x7));
        float4 a2 = *(const float4*)(ac + 4 * (ga1 ^ x7));
        float4 a3 = *(const float4*)(ac + 4 * ((ga1 + 1) ^ x7));

        const float sv[16] = {sj0.x,sj0.y,sj0.z,sj0.w, sj1.x,sj1.y,sj1.z,sj1.w,
                              sj2.x,sj2.y,sj2.z,sj2.w, sj3.x,sj3.y,sj3.z,sj3.w};
        const float av[16] = {a0.x,a0.y,a0.z,a0.w, a1.x,a1.y,a1.z,a1.w,
                              a2.x,a2.y,a2.z,a2.w, a3.x,a3.y,a3.z,a3.w};
        float pv[16]; float rs = 0.f;
        #pragma unroll
        for (int j = 0; j < 16; ++j) {
            float e = si + sv[j];
            e = fmaxf(e, 0.2f * e);             // LeakyReLU(0.2)
            pv[j] = __expf(e + av[j]);
            rs += pv[j];
        }
        union { unsigned u[4]; bf16x8 v; } pk0, pk1;
        #pragma unroll
        for (int j = 0; j < 4; ++j) {
            pk0.u[j] = pk_bf16(pv[2 * j], pv[2 * j + 1]);
            pk1.u[j] = pk_bf16(pv[8 + 2 * j], pv[9 + 2 * j]);
        }
        *(bf16x8*)(pbuf + m16 * 256 + 8 * ((8 * w + q) ^ x7)) = pk0.v;
        *(bf16x8*)(pbuf + m16 * 256 + 8 * ((8 * w + 4 + q) ^ x7)) = pk1.v;
        rsLds[t] = rs;
        asm volatile("s_waitcnt lgkmcnt(0)\n\ts_barrier" ::: "memory");  // P ready

        // MFMA: wave w owns g in [32w, 32w+32)
        f32x4 acc0 = {}, acc1 = {};
        const int gA = w * 32 + m16, gB = w * 32 + 16 + m16;
        #pragma unroll
        for (int kk = 0; kk < 8; ++kk) {
            const int jc = kk * 4 + q;
            bf16x8 af = *(const bf16x8*)(pbuf + m16 * 256 + 8 * (jc ^ x7));
            bf16x8 h0 = *(const bf16x8*)(hts + gA * 256 + 8 * (jc ^ x7));
            bf16x8 h1 = *(const bf16x8*)(hts + gB * 256 + 8 * (jc ^ x7));
            acc0 = __builtin_amdgcn_mfma_f32_16x16x32_bf16(af, h0, acc0, 0, 0, 0);
            acc1 = __builtin_amdgcn_mfma_f32_16x16x32_bf16(af, h1, acc1, 0, 0, 0);
        }

        // row sums: all 4 waves compute redundantly, benign same-value race;
        // keeps per-wave vmem-store count uniform (9)
        if (l < 16) {
            float sum = 0.f;
            #pragma unroll
            for (int w2 = 0; w2 < 4; ++w2)
                #pragma unroll
                for (int q2 = 0; q2 < 4; ++q2)
                    sum += rsLds[w2 * 64 + q2 * 16 + l];
            prs[(size_t)(js * BB + b) * NN + i0 + r * 16 + l] = sum;
        }

        const size_t pob = ((size_t)(js * BB + b) * NN + i0 + r * 16) * FF;
        #pragma unroll
        for (int rr = 0; rr < 4; ++rr) {
            const int irow = q * 4 + rr;
            po[pob + (size_t)irow * FF + w * 32 + m16]      = b16(acc0[rr]);
            po[pob + (size_t)irow * FF + w * 32 + 16 + m16] = b16(acc1[rr]);
        }
        // pbuf/rsLds consumed -> safe to overwrite next round (no vmem drain)
        asm volatile("s_waitcnt lgkmcnt(0)\n\ts_barrier" ::: "memory");
    }
}

// ---------------- Kernel 3: reduce 8 partials, normalize, bias ----------------------
__global__ __launch_bounds__(256) void k3_red(
    const uint16_t* __restrict__ po, const float* __restrict__ prs,
    const float* __restrict__ bias, float* __restrict__ out)
{
    const int idx = blockIdx.x * 256 + threadIdx.x;
    const int g = idx & 127;
    const int i = (idx >> 7) & (NN - 1);
    const int b = idx >> 18;
    float sum = 0.f, rsum = 0.f;
    #pragma unroll
    for (int js = 0; js < JS; ++js) {
        const size_t base = (size_t)(js * BB + b) * NN + i;
        union { unsigned u; float f; } cv;
        cv.u = ((unsigned)po[base * FF + g]) << 16;
        sum += cv.f;
        rsum += prs[base];
    }
    out[idx] = sum / rsum + bias[g];
}

extern "C" void kernel_launch(void* const* d_in, const int* in_sizes, int n_in,
                              void* d_out, int out_size, void* d_ws, size_t ws_size,
                              hipStream_t stream) {
    const float* x    = (const float*)d_in[0];
    const float* A    = (const float*)d_in[1];
    const float* W    = (const float*)d_in[2];
    const float* a_w  = (const float*)d_in[3];
    const float* a_b  = (const float*)d_in[4];
    const float* bias = (const float*)d_in[5];
    float* out = (float*)d_out;

    char* ws = (char*)d_ws;
    uint16_t* Ht = (uint16_t*)ws;                                  // 2 MB
    float* s = (float*)(ws + 2 * 1024 * 1024);                     // 32 KB (pad to 64K)
    uint16_t* po = (uint16_t*)(ws + 2 * 1024 * 1024 + 65536);      // 16 MB
    float* prs = (float*)(ws + 2 * 1024 * 1024 + 65536 + (size_t)JS * BB * NN * FF * 2);  // 256 KB

    k1_proj<<<BB * (NN / 16), 256, 0, stream>>>(x, W, a_w, a_b, Ht, s);
    k2_attn<<<BB * 8 * 8, 256, 0, stream>>>(A, Ht, s, po, prs);
    k3_red<<<(BB * NN * FF) / 256, 256, 0, stream>>>(po, prs, bias, out);
}

// Round 7
// 124.922 us; speedup vs baseline: 1.2665x; 1.0805x over previous
//
#include <hip/hip_runtime.h>
#include <hip/hip_bf16.h>
#include <stdint.h>

#define BB 4
#define NN 2048
#define FF 128

typedef __attribute__((ext_vector_type(8))) short bf16x8;
typedef __attribute__((ext_vector_type(4))) float f32x4;

__device__ inline unsigned pk_bf16(float a, float b) {
    union { float f; unsigned u; } x, y;
    x.f = a; y.f = b;
    unsigned xu = x.u + (0x7fffu + ((x.u >> 16) & 1u));
    unsigned yu = y.u + (0x7fffu + ((y.u >> 16) & 1u));
    return (xu >> 16) | (yu & 0xffff0000u);
}

#define XT_P 136
#define WT_P 136

// ---------------- Kernel 1: h = x@W via bf16 MFMA, s = h@a_w + a_b, Ht bf16 ---------
__global__ __launch_bounds__(256) void k1_proj(
    const float* __restrict__ x, const float* __restrict__ W,
    const float* __restrict__ a_w, const float* __restrict__ a_b,
    uint16_t* __restrict__ Ht, float* __restrict__ s_out)
{
    __shared__ uint16_t xt[16 * XT_P];
    __shared__ uint16_t Wt[128 * WT_P];
    __shared__ float sredw[4 * 16];

    const int t = threadIdx.x;
    const int w = t >> 6, l = t & 63;
    const int m16 = l & 15, q = l >> 4;
    const int b = blockIdx.x >> 7;
    const int n0 = (blockIdx.x & 127) << 4;

    const int c4 = (t & 31) * 4, kh = (t >> 5) * 16;
    float4 wr0[8], wr1[8];
    #pragma unroll
    for (int kk = 0; kk < 8; ++kk) {
        const int k = kh + 2 * kk;
        wr0[kk] = *(const float4*)(W + (size_t)k * 128 + c4);
        wr1[kk] = *(const float4*)(W + (size_t)(k + 1) * 128 + c4);
    }
    {
        const int row = t >> 4, c0 = (t & 15) * 8;
        const float* xr = x + ((size_t)(b * NN + n0 + row)) * FF + c0;
        const float4 v0 = *(const float4*)xr;
        const float4 v1 = *(const float4*)(xr + 4);
        unsigned* dst = (unsigned*)(xt + row * XT_P + c0);
        dst[0] = pk_bf16(v0.x, v0.y); dst[1] = pk_bf16(v0.z, v0.w);
        dst[2] = pk_bf16(v1.x, v1.y); dst[3] = pk_bf16(v1.z, v1.w);
    }
    #pragma unroll
    for (int kk = 0; kk < 8; ++kk) {
        const int k = kh + 2 * kk;
        *(unsigned*)(Wt + (c4 + 0) * WT_P + k) = pk_bf16(wr0[kk].x, wr1[kk].x);
        *(unsigned*)(Wt + (c4 + 1) * WT_P + k) = pk_bf16(wr0[kk].y, wr1[kk].y);
        *(unsigned*)(Wt + (c4 + 2) * WT_P + k) = pk_bf16(wr0[kk].z, wr1[kk].z);
        *(unsigned*)(Wt + (c4 + 3) * WT_P + k) = pk_bf16(wr0[kk].w, wr1[kk].w);
    }
    const int g0 = (2 * w) * 16 + m16, g1 = (2 * w + 1) * 16 + m16;
    const float aw0 = a_w[g0], aw1 = a_w[g1];
    __syncthreads();

    f32x4 acc0 = {}, acc1 = {};
    bf16x8 af[4];
    #pragma unroll
    for (int dk = 0; dk < 4; ++dk)
        af[dk] = *(const bf16x8*)(xt + m16 * XT_P + dk * 32 + q * 8);
    #pragma unroll
    for (int dk = 0; dk < 4; ++dk) {
        bf16x8 b0 = *(const bf16x8*)(Wt + g0 * WT_P + dk * 32 + q * 8);
        bf16x8 b1 = *(const bf16x8*)(Wt + g1 * WT_P + dk * 32 + q * 8);
        acc0 = __builtin_amdgcn_mfma_f32_16x16x32_bf16(af[dk], b0, acc0, 0, 0, 0);
        acc1 = __builtin_amdgcn_mfma_f32_16x16x32_bf16(af[dk], b1, acc1, 0, 0, 0);
    }

    float sp[4];
    #pragma unroll
    for (int r = 0; r < 4; ++r) sp[r] = acc0[r] * aw0 + acc1[r] * aw1;
    #pragma unroll
    for (int off = 1; off < 16; off <<= 1)
        #pragma unroll
        for (int r = 0; r < 4; ++r) sp[r] += __shfl_xor(sp[r], off, 64);
    if (m16 == 0) {
        #pragma unroll
        for (int r = 0; r < 4; ++r) sredw[w * 16 + q * 4 + r] = sp[r];
    }
    {
        uint2 o0 = { pk_bf16(acc0[0], acc0[1]), pk_bf16(acc0[2], acc0[3]) };
        uint2 o1 = { pk_bf16(acc1[0], acc1[1]), pk_bf16(acc1[2], acc1[3]) };
        *(uint2*)(Ht + ((size_t)(b * 128 + g0)) * NN + n0 + q * 4) = o0;
        *(uint2*)(Ht + ((size_t)(b * 128 + g1)) * NN + n0 + q * 4) = o1;
    }
    __syncthreads();
    if (t < 16)
        s_out[b * NN + n0 + t] = sredw[t] + sredw[16 + t] + sredw[32 + t] + sredw[48 + t] + a_b[0];
}

// ---------------- Kernel 2: register-resident split-K attention ----------------------
// Grid: js(8) x is(16) x b(4) = 512 blocks (2/CU), 256 thr (4 waves).
// Wave w: j-chunks {w, w+4} of the block's 256-j range; h-frags for its 2 chunks
// x ALL 8 g-tiles live in 64 VGPRs (loaded once). A loaded straight to registers
// (each dwordx4 spans 32 lines over 16 rows; A read exactly once). P never leaves
// the wave. Only 2 lgkm-only barriers/round for the cross-wave O reduction.
#define JS 8
#define IRND 8

__global__ __launch_bounds__(256, 2) void k2_attn(
    const float* __restrict__ A, const uint16_t* __restrict__ Ht,
    const float* __restrict__ s, uint16_t* __restrict__ po,
    float* __restrict__ prs)
{
    __shared__ float Opw[4][16 * 132];
    __shared__ float rsw[4][16];

    const int t = threadIdx.x;
    const int w = t >> 6, l = t & 63;
    const int m16 = l & 15, q = l >> 4;

    const int bx = blockIdx.x;
    const int js = bx & 7;
    const int is = (bx >> 3) & 15;
    const int b  = bx >> 7;
    const int j0 = js * 256;
    const int ibase = is * 128;

    const float* sb = s + b * NN;
    const float* Ab = A + (size_t)b * NN * NN;
    const uint16_t* Hb = Ht + (size_t)b * FF * NN;

    const int jc0 = j0 + w * 32 + q * 8;
    const int jc1 = j0 + (w + 4) * 32 + q * 8;

    // loop-invariant sj (16 values per lane)
    float4 sj00 = *(const float4*)(sb + jc0);
    float4 sj01 = *(const float4*)(sb + jc0 + 4);
    float4 sj10 = *(const float4*)(sb + jc1);
    float4 sj11 = *(const float4*)(sb + jc1 + 4);

    // h-fragments in registers: 2 chunks x 8 g-tiles (64 VGPR)
    bf16x8 hf0[8], hf1[8];
    #pragma unroll
    for (int gt = 0; gt < 8; ++gt) {
        const uint16_t* hp = Hb + (size_t)(gt * 16 + m16) * NN;
        hf0[gt] = *(const bf16x8*)(hp + jc0);
        hf1[gt] = *(const bf16x8*)(hp + jc1);
    }

    // round-0 A prefetch (lane: row ibase+m16, its 16 j's)
    const float* Ar = Ab + (size_t)(ibase + m16) * NN;
    float4 a00 = *(const float4*)(Ar + jc0);
    float4 a01 = *(const float4*)(Ar + jc0 + 4);
    float4 a10 = *(const float4*)(Ar + jc1);
    float4 a11 = *(const float4*)(Ar + jc1 + 4);
    float si = sb[ibase + m16];

    const size_t slice = (size_t)(js * BB + b);

    for (int r = 0; r < IRND; ++r) {
        const int i0r = ibase + r * 16;
        const int i0n = ibase + ((r + 1) & (IRND - 1)) * 16;

        // prefetch next round's A + si (full-round latency cover)
        const float* An = Ab + (size_t)(i0n + m16) * NN;
        float4 n00 = *(const float4*)(An + jc0);
        float4 n01 = *(const float4*)(An + jc0 + 4);
        float4 n10 = *(const float4*)(An + jc1);
        float4 n11 = *(const float4*)(An + jc1 + 4);
        const float sin_ = sb[i0n + m16];

        const float svv[16] = {sj00.x,sj00.y,sj00.z,sj00.w, sj01.x,sj01.y,sj01.z,sj01.w,
                               sj10.x,sj10.y,sj10.z,sj10.w, sj11.x,sj11.y,sj11.z,sj11.w};
        const float avv[16] = {a00.x,a00.y,a00.z,a00.w, a01.x,a01.y,a01.z,a01.w,
                               a10.x,a10.y,a10.z,a10.w, a11.x,a11.y,a11.z,a11.w};
        float pv[16]; float rs = 0.f;
        #pragma unroll
        for (int j = 0; j < 16; ++j) {
            float e = si + svv[j];
            e = fmaxf(e, 0.2f * e);               // LeakyReLU(0.2)
            pv[j] = __expf(e + avv[j]);
            rs += pv[j];
        }
        union { unsigned u[4]; bf16x8 v; } fa0, fa1;
        #pragma unroll
        for (int j = 0; j < 4; ++j) {
            fa0.u[j] = pk_bf16(pv[2 * j], pv[2 * j + 1]);
            fa1.u[j] = pk_bf16(pv[8 + 2 * j], pv[9 + 2 * j]);
        }

        // 16 MFMAs: this wave's P x all 128 g (h-frags in regs; 8 indep chains)
        f32x4 acc[8];
        #pragma unroll
        for (int gt = 0; gt < 8; ++gt) {
            f32x4 z = {0.f, 0.f, 0.f, 0.f};
            z = __builtin_amdgcn_mfma_f32_16x16x32_bf16(fa0.v, hf0[gt], z, 0, 0, 0);
            acc[gt] = __builtin_amdgcn_mfma_f32_16x16x32_bf16(fa1.v, hf1[gt], z, 0, 0, 0);
        }

        // row-sum partials: reduce over q within wave (rows = m16)
        rs += __shfl_xor(rs, 16, 64);
        rs += __shfl_xor(rs, 32, 64);
        if (q == 0) rsw[w][m16] = rs;

        // stage this wave's O partial (stride 132 -> 2-way-max bank aliasing)
        #pragma unroll
        for (int gt = 0; gt < 8; ++gt)
            #pragma unroll
            for (int rr = 0; rr < 4; ++rr)
                Opw[w][(q * 4 + rr) * 132 + gt * 16 + m16] = acc[gt][rr];
        asm volatile("s_waitcnt lgkmcnt(0)\n\ts_barrier" ::: "memory");  // no vmem drain

        // cross-wave reduce + store (unnormalized partials; k3 divides)
        {
            const int row = t >> 4, k8 = (t & 15) * 8;
            float v[8] = {0.f,0.f,0.f,0.f,0.f,0.f,0.f,0.f};
            #pragma unroll
            for (int sl = 0; sl < 4; ++sl) {
                float4 u0 = *(const float4*)&Opw[sl][row * 132 + k8];
                float4 u1 = *(const float4*)&Opw[sl][row * 132 + k8 + 4];
                v[0] += u0.x; v[1] += u0.y; v[2] += u0.z; v[3] += u0.w;
                v[4] += u1.x; v[5] += u1.y; v[6] += u1.z; v[7] += u1.w;
            }
            unsigned* op = (unsigned*)(po + ((slice * NN + i0r + row) * FF + k8));
            op[0] = pk_bf16(v[0], v[1]); op[1] = pk_bf16(v[2], v[3]);
            op[2] = pk_bf16(v[4], v[5]); op[3] = pk_bf16(v[6], v[7]);
            if (t < 16)
                prs[slice * NN + i0r + t] = rsw[0][t] + rsw[1][t] + rsw[2][t] + rsw[3][t];
        }
        asm volatile("s_waitcnt lgkmcnt(0)\n\ts_barrier" ::: "memory");  // Opw/rsw reuse

        a00 = n00; a01 = n01; a10 = n10; a11 = n11; si = sin_;
    }
}

// ---------------- Kernel 3: reduce 8 partials, normalize, bias ----------------------
__global__ __launch_bounds__(256) void k3_red(
    const uint16_t* __restrict__ po, const float* __restrict__ prs,
    const float* __restrict__ bias, float* __restrict__ out)
{
    const int idx = blockIdx.x * 256 + threadIdx.x;
    const int g = idx & 127;
    const int i = (idx >> 7) & (NN - 1);
    const int b = idx >> 18;
    float sum = 0.f, rsum = 0.f;
    #pragma unroll
    for (int js = 0; js < JS; ++js) {
        const size_t base = (size_t)(js * BB + b) * NN + i;
        union { unsigned u; float f; } cv;
        cv.u = ((unsigned)po[base * FF + g]) << 16;
        sum += cv.f;
        rsum += prs[base];
    }
    out[idx] = sum / rsum + bias[g];
}

extern "C" void kernel_launch(void* const* d_in, const int* in_sizes, int n_in,
                              void* d_out, int out_size, void* d_ws, size_t ws_size,
                              hipStream_t stream) {
    const float* x    = (const float*)d_in[0];
    const float* A    = (const float*)d_in[1];
    const float* W    = (const float*)d_in[2];
    const float* a_w  = (const float*)d_in[3];
    const float* a_b  = (const float*)d_in[4];
    const float* bias = (const float*)d_in[5];
    float* out = (float*)d_out;

    char* ws = (char*)d_ws;
    uint16_t* Ht = (uint16_t*)ws;                                  // 2 MB
    float* s = (float*)(ws + 2 * 1024 * 1024);                     // 32 KB (pad to 64K)
    uint16_t* po = (uint16_t*)(ws + 2 * 1024 * 1024 + 65536);      // 16 MB
    float* prs = (float*)(ws + 2 * 1024 * 1024 + 65536 + (size_t)JS * BB * NN * FF * 2);  // 256 KB

    k1_proj<<<BB * (NN / 16), 256, 0, stream>>>(x, W, a_w, a_b, Ht, s);
    k2_attn<<<JS * 16 * BB, 256, 0, stream>>>(A, Ht, s, po, prs);
    k3_red<<<(BB * NN * FF) / 256, 256, 0, stream>>>(po, prs, bias, out);
}